// Round 1
// 356.535 us; speedup vs baseline: 1.2116x; 1.2116x over previous
//
#include <hip/hip_runtime.h>

typedef unsigned short u16;
typedef short bf16x8 __attribute__((ext_vector_type(8)));
typedef float f32x4 __attribute__((ext_vector_type(4)));

#define B_  4
#define T_  2048
#define C_  1024
#define NH_ 16
#define HD_ 64

// async global->LDS, 16B/lane; LDS dest = wave-uniform base + lane*16.
__device__ __forceinline__ void gload16(const u16* g, u16* lds) {
  __builtin_amdgcn_global_load_lds(
      (const __attribute__((address_space(1))) void*)g,
      (__attribute__((address_space(3))) void*)lds, 16, 0, 0);
}

__device__ __forceinline__ u16 f2bf(float f) {  // RNE float->bf16
  union { float f; unsigned u; } x; x.f = f;
  unsigned r = x.u + 0x7fffu + ((x.u >> 16) & 1u);
  return (u16)(r >> 16);
}

// ---------------------------------------------------------------------------
// x (f32, all batches) -> bf16
// ---------------------------------------------------------------------------
__global__ __launch_bounds__(256) void convert_x(const float* __restrict__ in,
                                                 u16* __restrict__ out) {
  int i = (blockIdx.x * 256 + threadIdx.x) * 8;
  float4 a = *(const float4*)(in + i);
  float4 b = *(const float4*)(in + i + 4);
  u16 t[8] = {f2bf(a.x), f2bf(a.y), f2bf(a.z), f2bf(a.w),
              f2bf(b.x), f2bf(b.y), f2bf(b.z), f2bf(b.w)};
  *(uint4*)(out + i) = *(const uint4*)t;
}

// ---------------------------------------------------------------------------
// Weight transpose+convert: f32 [R][Cc] -> bf16 [Cc][R]
// ---------------------------------------------------------------------------
__global__ __launch_bounds__(256) void transpose_w(const float* __restrict__ in,
                                                   u16* __restrict__ out,
                                                   int R, int Cc) {
  int r0 = blockIdx.x * 64, c0 = blockIdx.y * 64;
  __shared__ __attribute__((aligned(16))) u16 tile[64][72];
  int tid = threadIdx.x;
#pragma unroll
  for (int it = 0; it < 4; ++it) {
    int chunk = it * 256 + tid;          // 0..1023
    int row = chunk >> 4, c4 = chunk & 15;
    float4 v = *(const float4*)(in + (size_t)(r0 + row) * Cc + c0 + c4 * 4);
    tile[row][c4 * 4 + 0] = f2bf(v.x);
    tile[row][c4 * 4 + 1] = f2bf(v.y);
    tile[row][c4 * 4 + 2] = f2bf(v.z);
    tile[row][c4 * 4 + 3] = f2bf(v.w);
  }
  __syncthreads();
#pragma unroll
  for (int it = 0; it < 2; ++it) {
    int chunk = it * 256 + tid;
    int row = chunk >> 3, c8 = chunk & 7;
    uint4 v; u16* tv = (u16*)&v;
#pragma unroll
    for (int k = 0; k < 8; ++k) tv[k] = tile[c8 * 8 + k][row];
    *(uint4*)(out + (size_t)(c0 + row) * R + r0 + c8 * 8) = v;
  }
}

// ---------------------------------------------------------------------------
// m97-style async BT GEMM mainloop: 128x128 tile of A[M,K] @ Bt[N,K]^T.
// global_load_lds width-16 staging, unpadded stride-32 LDS (874 TF class).
// ---------------------------------------------------------------------------
__device__ __forceinline__ void gemm_bt_tile(const u16* __restrict__ A,
                                             const u16* __restrict__ Bt,
                                             int Kdim, int m0, int n0,
                                             u16* sA, u16* sB, f32x4 acc[4][4]) {
  int tid = threadIdx.x;
  int w = tid >> 6, l = tid & 63, li = l & 15, quad = l >> 4;
  int wm = (w >> 1) * 64, wn = (w & 1) * 64;
  f32x4 zero = {0.f, 0.f, 0.f, 0.f};
#pragma unroll
  for (int i = 0; i < 4; ++i)
#pragma unroll
    for (int j = 0; j < 4; ++j) acc[i][j] = zero;

  for (int k0 = 0; k0 < Kdim; k0 += 32) {
#pragma unroll
    for (int r = 0; r < 2; ++r) {
      int chunk = r * 256 + tid;           // 0..511, lane-contiguous per wave
      int row = chunk >> 2, c8 = chunk & 3;
      gload16(A  + (size_t)(m0 + row) * Kdim + k0 + c8 * 8, sA + chunk * 8);
      gload16(Bt + (size_t)(n0 + row) * Kdim + k0 + c8 * 8, sB + chunk * 8);
    }
    __syncthreads();
    bf16x8 af[4], bfr[4];
#pragma unroll
    for (int i = 0; i < 4; ++i)
      af[i] = *(const bf16x8*)(sA + (wm + i * 16 + li) * 32 + quad * 8);
#pragma unroll
    for (int j = 0; j < 4; ++j)
      bfr[j] = *(const bf16x8*)(sB + (wn + j * 16 + li) * 32 + quad * 8);
#pragma unroll
    for (int i = 0; i < 4; ++i)
#pragma unroll
      for (int j = 0; j < 4; ++j)
        acc[i][j] = __builtin_amdgcn_mfma_f32_16x16x32_bf16(af[i], bfr[j], acc[i][j], 0, 0, 0);
    __syncthreads();
  }
}

// ---------------------------------------------------------------------------
// QKV GEMM, all batches: X[8192,1024] @ watT[3072,1024]^T.
// Epilogue scatters Q,K as [b,h,t,d] and V directly transposed [b,h,d,t]
// (vectorized 8B stores: 4 consecutive t per lane).
// ---------------------------------------------------------------------------
__global__ __launch_bounds__(256) void gemm_qkv(const u16* __restrict__ X,
                                                const u16* __restrict__ WT,
                                                u16* __restrict__ Qb,
                                                u16* __restrict__ Kb,
                                                u16* __restrict__ Vt) {
  __shared__ __attribute__((aligned(16))) u16 sA[128 * 32];
  __shared__ __attribute__((aligned(16))) u16 sB[128 * 32];
  f32x4 acc[4][4];
  int m0 = blockIdx.x * 128, n0 = blockIdx.y * 128;
  gemm_bt_tile(X, WT, C_, m0, n0, sA, sB, acc);

  int tid = threadIdx.x;
  int w = tid >> 6, l = tid & 63, li = l & 15, quad = l >> 4;
  int wm = (w >> 1) * 64, wn = (w & 1) * 64;
#pragma unroll
  for (int i = 0; i < 4; ++i)
#pragma unroll
    for (int j = 0; j < 4; ++j) {
      int n = n0 + wn + j * 16 + li;
      int which = n >> 10, cc = n & (C_ - 1);
      int h = cc >> 6, d = cc & (HD_ - 1);
      int mb = m0 + wm + i * 16 + quad * 4;
      int b = mb >> 11, t0 = mb & (T_ - 1);
      if (which == 2) {
        u16 tv[4] = {f2bf(acc[i][j][0]), f2bf(acc[i][j][1]),
                     f2bf(acc[i][j][2]), f2bf(acc[i][j][3])};
        *(uint2*)(Vt + ((size_t)(b * NH_ + h) * HD_ + d) * T_ + t0) = *(const uint2*)tv;
      } else {
        u16* dst = (which == 0) ? Qb : Kb;
#pragma unroll
        for (int r = 0; r < 4; ++r)
          dst[((size_t)(b * NH_ + h) * T_ + t0 + r) * HD_ + d] = f2bf(acc[i][j][r]);
      }
    }
}

// ---------------------------------------------------------------------------
// Proj GEMM, all batches: Y[8192,1024] @ wprojT[1024,1024]^T -> f32 out
// ---------------------------------------------------------------------------
__global__ __launch_bounds__(256) void gemm_proj(const u16* __restrict__ Y,
                                                 const u16* __restrict__ WT,
                                                 float* __restrict__ Out) {
  __shared__ __attribute__((aligned(16))) u16 sA[128 * 32];
  __shared__ __attribute__((aligned(16))) u16 sB[128 * 32];
  f32x4 acc[4][4];
  int m0 = blockIdx.x * 128, n0 = blockIdx.y * 128;
  gemm_bt_tile(Y, WT, C_, m0, n0, sA, sB, acc);

  int tid = threadIdx.x;
  int w = tid >> 6, l = tid & 63, li = l & 15, quad = l >> 4;
  int wm = (w >> 1) * 64, wn = (w & 1) * 64;
#pragma unroll
  for (int i = 0; i < 4; ++i)
#pragma unroll
    for (int j = 0; j < 4; ++j)
#pragma unroll
      for (int r = 0; r < 4; ++r) {
        int m = m0 + wm + i * 16 + quad * 4 + r;
        int n = n0 + wn + j * 16 + li;
        Out[(size_t)m * C_ + n] = acc[i][j][r];
      }
}

// ---------------------------------------------------------------------------
// Flash attention v2: QBLK=128 (8 waves x 16 rows), KVBLK=64.
// - Q direct global->reg (no sQ).
// - K/V double-buffered async global_load_lds staging, prefetch depth 1,
//   XOR-swizzled via SOURCE address (linear LDS dest), swizzled ds_read.
// - sP: own-wave 16-row stripe -> no barrier between write and PV read.
// - row-sum via MFMA against all-ones B fragment (no shuffle sum-reduce).
// - 1 __syncthreads per kv tile; s_setprio around MFMA clusters.
// LDS = 2*8K (K) + 2*8K (V) + 16K (P) = 48 KiB -> 3 blocks/CU.
// ---------------------------------------------------------------------------
__global__ __launch_bounds__(512) void attn_k(const u16* __restrict__ Q,
                                              const u16* __restrict__ K,
                                              const u16* __restrict__ Vt,
                                              u16* __restrict__ Y) {
  int qt = (gridDim.x - 1) - blockIdx.x;   // heavy blocks first
  int bh = blockIdx.y;
  int tid = threadIdx.x;
  int w = tid >> 6, l = tid & 63, li = l & 15, quad = l >> 4;
  int q0 = qt * 128;

  __shared__ __attribute__((aligned(16))) u16 sK[2][64 * 64];
  __shared__ __attribute__((aligned(16))) u16 sV[2][64 * 64];
  __shared__ __attribute__((aligned(16))) u16 sP[128 * 64];

  // Q fragments straight from global (read once; rows 16w+li, cols quad*8)
  bf16x8 qf0, qf1;
  {
    const u16* qp = Q + ((size_t)bh * T_ + q0 + 16 * w + li) * HD_;
    qf0 = *(const bf16x8*)(qp + quad * 8);
    qf1 = *(const bf16x8*)(qp + 32 + quad * 8);
  }

  const u16* kbase = K + (size_t)bh * T_ * HD_;
  const u16* vbase = Vt + (size_t)bh * HD_ * T_;
  // staging geometry: 512 threads x 16B covers one 64x64 bf16 tile.
  int srow = tid >> 3, sc8 = tid & 7;
  int scol = (sc8 ^ (srow & 7)) * 8;       // source-side XOR swizzle (16B granule)

  f32x4 o[4], o_l;
  f32x4 zero = {0.f, 0.f, 0.f, 0.f};
#pragma unroll
  for (int j = 0; j < 4; ++j) o[j] = zero;
  o_l = zero;
  float mrow[4] = {-1e30f, -1e30f, -1e30f, -1e30f};
  const float csc = 0.125f * 1.44269504088896f;  // 1/sqrt(64) * log2(e)

  bf16x8 ones;
#pragma unroll
  for (int i = 0; i < 8; ++i) ones[i] = (short)0x3F80;  // bf16 1.0

  int nkv = 2 * qt + 2;

  // prologue: stage tile 0 into buffer 0
  {
    gload16(kbase + (size_t)srow * HD_ + scol, sK[0] + tid * 8);
    gload16(vbase + (size_t)srow * T_ + scol, sV[0] + tid * 8);
  }
  __syncthreads();   // implicit vmcnt(0) drain

  int cur = 0;
  for (int kvt = 0; kvt < nkv; ++kvt) {
    int kv0 = kvt * 64;
    // prefetch next tile into the other buffer (issue early, drain at barrier)
    if (kvt + 1 < nkv) {
      int nv0 = kv0 + 64;
      gload16(kbase + (size_t)(nv0 + srow) * HD_ + scol, sK[cur ^ 1] + tid * 8);
      gload16(vbase + (size_t)srow * T_ + nv0 + scol, sV[cur ^ 1] + tid * 8);
    }

    bool wave_skip = (kv0 > q0 + 16 * w + 15);   // wave entirely above diagonal
    if (!wave_skip) {
      const u16* sk = sK[cur];
      f32x4 s[4];
      __builtin_amdgcn_s_setprio(1);
#pragma unroll
      for (int j = 0; j < 4; ++j) {
        int rowk = j * 16 + li;
        bf16x8 kf0 = *(const bf16x8*)(sk + rowk * 64 + ((quad ^ (rowk & 7)) * 8));
        bf16x8 kf1 = *(const bf16x8*)(sk + rowk * 64 + (((4 + quad) ^ (rowk & 7)) * 8));
        f32x4 z = zero;
        z = __builtin_amdgcn_mfma_f32_16x16x32_bf16(qf0, kf0, z, 0, 0, 0);
        z = __builtin_amdgcn_mfma_f32_16x16x32_bf16(qf1, kf1, z, 0, 0, 0);
        s[j] = z;
      }
      __builtin_amdgcn_s_setprio(0);

      if (kvt >= nkv - 2) {                      // diagonal band: causal mask
#pragma unroll
        for (int j = 0; j < 4; ++j)
#pragma unroll
          for (int r = 0; r < 4; ++r) {
            int qrow = q0 + 16 * w + quad * 4 + r;
            int kcol = kv0 + j * 16 + li;
            if (kcol > qrow) s[j][r] = -1e30f;
          }
      }

      // running max (only reduce left: 4x shfl chain over li group)
      float mnew[4], alpha[4];
#pragma unroll
      for (int r = 0; r < 4; ++r) {
        float v = fmaxf(fmaxf(s[0][r], s[1][r]), fmaxf(s[2][r], s[3][r]));
#pragma unroll
        for (int off = 1; off < 16; off <<= 1) v = fmaxf(v, __shfl_xor(v, off, 16));
        mnew[r] = fmaxf(mrow[r], v);
        alpha[r] = exp2f((mrow[r] - mnew[r]) * csc);
        mrow[r] = mnew[r];
      }

      // P = exp2((s-m)*csc), write bf16 to own-wave sP stripe (swizzled)
#pragma unroll
      for (int r = 0; r < 4; ++r) {
        float mc = mnew[r] * csc;
        int prow = 16 * w + quad * 4 + r;
        int swz = (prow & 7) * 8;
#pragma unroll
        for (int j = 0; j < 4; ++j) {
          float p = exp2f(s[j][r] * csc - mc);
          sP[prow * 64 + ((j * 16 + li) ^ swz)] = f2bf(p);
        }
#pragma unroll
        for (int j = 0; j < 4; ++j) o[j][r] *= alpha[r];
        o_l[r] *= alpha[r];
      }

      // PV + row-sum: own-wave stripe only -> in-wave LDS ordering suffices
      int prow2 = 16 * w + li;
      bf16x8 pf0 = *(const bf16x8*)(sP + prow2 * 64 + ((quad ^ (prow2 & 7)) * 8));
      bf16x8 pf1 = *(const bf16x8*)(sP + prow2 * 64 + (((4 + quad) ^ (prow2 & 7)) * 8));
      const u16* sv = sV[cur];
      __builtin_amdgcn_s_setprio(1);
#pragma unroll
      for (int j = 0; j < 4; ++j) {
        int rowv = j * 16 + li;
        bf16x8 vf0 = *(const bf16x8*)(sv + rowv * 64 + ((quad ^ (rowv & 7)) * 8));
        bf16x8 vf1 = *(const bf16x8*)(sv + rowv * 64 + (((4 + quad) ^ (rowv & 7)) * 8));
        o[j] = __builtin_amdgcn_mfma_f32_16x16x32_bf16(pf0, vf0, o[j], 0, 0, 0);
        o[j] = __builtin_amdgcn_mfma_f32_16x16x32_bf16(pf1, vf1, o[j], 0, 0, 0);
      }
      o_l = __builtin_amdgcn_mfma_f32_16x16x32_bf16(pf0, ones, o_l, 0, 0, 0);
      o_l = __builtin_amdgcn_mfma_f32_16x16x32_bf16(pf1, ones, o_l, 0, 0, 0);
      __builtin_amdgcn_s_setprio(0);
    }

    __syncthreads();   // drains prefetch vmcnt + guards buffer swap
    cur ^= 1;
  }

  int b = bh >> 4, h = bh & (NH_ - 1);
  float rinv[4];
#pragma unroll
  for (int r = 0; r < 4; ++r) rinv[r] = 1.0f / fmaxf(o_l[r], 1e-20f);
#pragma unroll
  for (int j = 0; j < 4; ++j)
#pragma unroll
    for (int r = 0; r < 4; ++r) {
      int t = q0 + 16 * w + quad * 4 + r;
      int d = j * 16 + li;
      Y[((size_t)b * T_ + t) * C_ + h * HD_ + d] = f2bf(o[j][r] * rinv[r]);
    }
}

// ---------------------------------------------------------------------------
extern "C" void kernel_launch(void* const* d_in, const int* in_sizes, int n_in,
                              void* d_out, int out_size, void* d_ws, size_t ws_size,
                              hipStream_t stream) {
  (void)in_sizes; (void)n_in; (void)out_size; (void)ws_size;
  const float* x      = (const float*)d_in[0];   // [B,T,C] f32
  const float* w_attn = (const float*)d_in[1];   // [C,3C]  f32
  const float* w_proj = (const float*)d_in[2];   // [C,C]   f32
  float* out = (float*)d_out;                    // [B,T,C] f32

  const size_t NTOK = (size_t)B_ * T_ * C_;      // 8.39M elems
  u16* watT   = (u16*)d_ws;                      // 3.15M
  u16* wprojT = watT   + (size_t)3 * C_ * C_;    // 1.05M
  u16* xbf    = wprojT + (size_t)C_ * C_;        // 8.39M (yb overlays this)
  u16* qb     = xbf  + NTOK;                     // 8.39M [b,h,t,d]
  u16* kb     = qb   + NTOK;                     // 8.39M [b,h,t,d]
  u16* vtb    = kb   + NTOK;                     // 8.39M [b,h,d,t]
  u16* yb     = xbf;                             // overlay: xbf dead after qkv
  // total ws: 37.8M u16 = 75.5 MB

  transpose_w<<<dim3(16, 48), 256, 0, stream>>>(w_attn, watT, C_, 3 * C_);
  transpose_w<<<dim3(16, 16), 256, 0, stream>>>(w_proj, wprojT, C_, C_);
  convert_x<<<dim3(4096), 256, 0, stream>>>(x, xbf);
  gemm_qkv<<<dim3(64, 24), 256, 0, stream>>>(xbf, watT, qb, kb, vtb);
  attn_k<<<dim3(16, 64), 512, 0, stream>>>(qb, kb, vtb, yb);
  gemm_proj<<<dim3(64, 8), 256, 0, stream>>>(yb, wprojT, out);
}

// Round 2
// 278.243 us; speedup vs baseline: 1.5525x; 1.2814x over previous
//
#include <hip/hip_runtime.h>

typedef unsigned short u16;
typedef short bf16x8 __attribute__((ext_vector_type(8)));
typedef float f32x4 __attribute__((ext_vector_type(4)));

#define B_  4
#define T_  2048
#define C_  1024
#define NH_ 16
#define HD_ 64

// async global->LDS, 16B/lane; LDS dest = wave-uniform base + lane*16.
__device__ __forceinline__ void gload16(const u16* g, u16* lds) {
  __builtin_amdgcn_global_load_lds(
      (const __attribute__((address_space(1))) void*)g,
      (__attribute__((address_space(3))) void*)lds, 16, 0, 0);
}

__device__ __forceinline__ u16 f2bf(float f) {  // RNE float->bf16
  union { float f; unsigned u; } x; x.f = f;
  unsigned r = x.u + 0x7fffu + ((x.u >> 16) & 1u);
  return (u16)(r >> 16);
}

// ---------------------------------------------------------------------------
// x (f32, all batches) -> bf16
// ---------------------------------------------------------------------------
__global__ __launch_bounds__(256) void convert_x(const float* __restrict__ in,
                                                 u16* __restrict__ out) {
  int i = (blockIdx.x * 256 + threadIdx.x) * 8;
  float4 a = *(const float4*)(in + i);
  float4 b = *(const float4*)(in + i + 4);
  u16 t[8] = {f2bf(a.x), f2bf(a.y), f2bf(a.z), f2bf(a.w),
              f2bf(b.x), f2bf(b.y), f2bf(b.z), f2bf(b.w)};
  *(uint4*)(out + i) = *(const uint4*)t;
}

// ---------------------------------------------------------------------------
// Weight transpose+convert: f32 [R][Cc] -> bf16 [Cc][R]
// ---------------------------------------------------------------------------
__global__ __launch_bounds__(256) void transpose_w(const float* __restrict__ in,
                                                   u16* __restrict__ out,
                                                   int R, int Cc) {
  int r0 = blockIdx.x * 64, c0 = blockIdx.y * 64;
  __shared__ __attribute__((aligned(16))) u16 tile[64][72];
  int tid = threadIdx.x;
#pragma unroll
  for (int it = 0; it < 4; ++it) {
    int chunk = it * 256 + tid;          // 0..1023
    int row = chunk >> 4, c4 = chunk & 15;
    float4 v = *(const float4*)(in + (size_t)(r0 + row) * Cc + c0 + c4 * 4);
    tile[row][c4 * 4 + 0] = f2bf(v.x);
    tile[row][c4 * 4 + 1] = f2bf(v.y);
    tile[row][c4 * 4 + 2] = f2bf(v.z);
    tile[row][c4 * 4 + 3] = f2bf(v.w);
  }
  __syncthreads();
#pragma unroll
  for (int it = 0; it < 2; ++it) {
    int chunk = it * 256 + tid;
    int row = chunk >> 3, c8 = chunk & 7;
    uint4 v; u16* tv = (u16*)&v;
#pragma unroll
    for (int k = 0; k < 8; ++k) tv[k] = tile[c8 * 8 + k][row];
    *(uint4*)(out + (size_t)(c0 + row) * R + r0 + c8 * 8) = v;
  }
}

// ---------------------------------------------------------------------------
// m97-style async BT GEMM mainloop: 128x128 tile of A[M,K] @ Bt[N,K]^T.
// global_load_lds width-16 staging, unpadded stride-32 LDS (874 TF class).
// ---------------------------------------------------------------------------
__device__ __forceinline__ void gemm_bt_tile(const u16* __restrict__ A,
                                             const u16* __restrict__ Bt,
                                             int Kdim, int m0, int n0,
                                             u16* sA, u16* sB, f32x4 acc[4][4]) {
  int tid = threadIdx.x;
  int w = tid >> 6, l = tid & 63, li = l & 15, quad = l >> 4;
  int wm = (w >> 1) * 64, wn = (w & 1) * 64;
  f32x4 zero = {0.f, 0.f, 0.f, 0.f};
#pragma unroll
  for (int i = 0; i < 4; ++i)
#pragma unroll
    for (int j = 0; j < 4; ++j) acc[i][j] = zero;

  for (int k0 = 0; k0 < Kdim; k0 += 32) {
#pragma unroll
    for (int r = 0; r < 2; ++r) {
      int chunk = r * 256 + tid;           // 0..511, lane-contiguous per wave
      int row = chunk >> 2, c8 = chunk & 3;
      gload16(A  + (size_t)(m0 + row) * Kdim + k0 + c8 * 8, sA + chunk * 8);
      gload16(Bt + (size_t)(n0 + row) * Kdim + k0 + c8 * 8, sB + chunk * 8);
    }
    __syncthreads();
    bf16x8 af[4], bfr[4];
#pragma unroll
    for (int i = 0; i < 4; ++i)
      af[i] = *(const bf16x8*)(sA + (wm + i * 16 + li) * 32 + quad * 8);
#pragma unroll
    for (int j = 0; j < 4; ++j)
      bfr[j] = *(const bf16x8*)(sB + (wn + j * 16 + li) * 32 + quad * 8);
#pragma unroll
    for (int i = 0; i < 4; ++i)
#pragma unroll
      for (int j = 0; j < 4; ++j)
        acc[i][j] = __builtin_amdgcn_mfma_f32_16x16x32_bf16(af[i], bfr[j], acc[i][j], 0, 0, 0);
    __syncthreads();
  }
}

// ---------------------------------------------------------------------------
// QKV GEMM, all batches: X[8192,1024] @ watT[3072,1024]^T.
// Epilogue scatters Q,K as [b,h,t,d] and V directly transposed [b,h,d,t]
// (vectorized 8B stores: 4 consecutive t per lane).
// ---------------------------------------------------------------------------
__global__ __launch_bounds__(256) void gemm_qkv(const u16* __restrict__ X,
                                                const u16* __restrict__ WT,
                                                u16* __restrict__ Qb,
                                                u16* __restrict__ Kb,
                                                u16* __restrict__ Vt) {
  __shared__ __attribute__((aligned(16))) u16 sA[128 * 32];
  __shared__ __attribute__((aligned(16))) u16 sB[128 * 32];
  f32x4 acc[4][4];
  int m0 = blockIdx.x * 128, n0 = blockIdx.y * 128;
  gemm_bt_tile(X, WT, C_, m0, n0, sA, sB, acc);

  int tid = threadIdx.x;
  int w = tid >> 6, l = tid & 63, li = l & 15, quad = l >> 4;
  int wm = (w >> 1) * 64, wn = (w & 1) * 64;
#pragma unroll
  for (int i = 0; i < 4; ++i)
#pragma unroll
    for (int j = 0; j < 4; ++j) {
      int n = n0 + wn + j * 16 + li;
      int which = n >> 10, cc = n & (C_ - 1);
      int h = cc >> 6, d = cc & (HD_ - 1);
      int mb = m0 + wm + i * 16 + quad * 4;
      int b = mb >> 11, t0 = mb & (T_ - 1);
      if (which == 2) {
        u16 tv[4] = {f2bf(acc[i][j][0]), f2bf(acc[i][j][1]),
                     f2bf(acc[i][j][2]), f2bf(acc[i][j][3])};
        *(uint2*)(Vt + ((size_t)(b * NH_ + h) * HD_ + d) * T_ + t0) = *(const uint2*)tv;
      } else {
        u16* dst = (which == 0) ? Qb : Kb;
#pragma unroll
        for (int r = 0; r < 4; ++r)
          dst[((size_t)(b * NH_ + h) * T_ + t0 + r) * HD_ + d] = f2bf(acc[i][j][r]);
      }
    }
}

// ---------------------------------------------------------------------------
// Proj GEMM, all batches: Y[8192,1024] @ wprojT[1024,1024]^T -> f32 out
// ---------------------------------------------------------------------------
__global__ __launch_bounds__(256) void gemm_proj(const u16* __restrict__ Y,
                                                 const u16* __restrict__ WT,
                                                 float* __restrict__ Out) {
  __shared__ __attribute__((aligned(16))) u16 sA[128 * 32];
  __shared__ __attribute__((aligned(16))) u16 sB[128 * 32];
  f32x4 acc[4][4];
  int m0 = blockIdx.x * 128, n0 = blockIdx.y * 128;
  gemm_bt_tile(Y, WT, C_, m0, n0, sA, sB, acc);

  int tid = threadIdx.x;
  int w = tid >> 6, l = tid & 63, li = l & 15, quad = l >> 4;
  int wm = (w >> 1) * 64, wn = (w & 1) * 64;
#pragma unroll
  for (int i = 0; i < 4; ++i)
#pragma unroll
    for (int j = 0; j < 4; ++j)
#pragma unroll
      for (int r = 0; r < 4; ++r) {
        int m = m0 + wm + i * 16 + quad * 4 + r;
        int n = n0 + wn + j * 16 + li;
        Out[(size_t)m * C_ + n] = acc[i][j][r];
      }
}

// ---------------------------------------------------------------------------
// Flash attention v3: balanced q-tile PAIRING. Block bx handles q-tiles
// (15-bx) then (bx): every block = exactly 34 kv-tiles -> 512 uniform blocks,
// exactly 2 resident/CU (LDS padded past 53.3KB to forbid a lopsided 3rd).
// Per-tile softmax VALU cut: defer-max (T13, THR=8 in exp2 domain) skips the
// rescale on most tiles; v_cvt_pk_bf16_f32 packs P->bf16 (8 ops vs ~48).
// K/V double-buffered async global_load_lds, source-side XOR swizzle;
// prefetch chains across the job boundary (both jobs start at kv0=0).
// ---------------------------------------------------------------------------
__global__ __launch_bounds__(512, 4) void attn_k(const u16* __restrict__ Q,
                                                 const u16* __restrict__ K,
                                                 const u16* __restrict__ Vt,
                                                 u16* __restrict__ Y) {
  int bx = blockIdx.x;                     // 0..7
  int bh = blockIdx.y;
  int tid = threadIdx.x;
  int w = tid >> 6, l = tid & 63, li = l & 15, quad = l >> 4;
  const int jqA = 15 - bx;                 // heavy job: 8..15
  const int jqB = bx;                      // light job: 0..7

  __shared__ __attribute__((aligned(16))) u16 sK[2][64 * 64];
  __shared__ __attribute__((aligned(16))) u16 sV[2][64 * 64];
  __shared__ __attribute__((aligned(16))) u16 sP[128 * 64];
  __shared__ u16 sPad[3200];               // force LDS>53.3KB: exactly 2 blk/CU
  if ((int)blockIdx.z == 1) sPad[tid] = 0; // never true; defeats DCE

  // Q fragments for both jobs straight from global (read once)
  bf16x8 qf[2][2];
#pragma unroll
  for (int s = 0; s < 2; ++s) {
    int qt = s ? jqB : jqA;
    const u16* qp = Q + ((size_t)bh * T_ + qt * 128 + 16 * w + li) * HD_;
    qf[s][0] = *(const bf16x8*)(qp + quad * 8);
    qf[s][1] = *(const bf16x8*)(qp + 32 + quad * 8);
  }

  const u16* kbase = K + (size_t)bh * T_ * HD_;
  const u16* vbase = Vt + (size_t)bh * HD_ * T_;
  // staging geometry: 512 threads x 16B covers one 64x64 bf16 tile.
  int srow = tid >> 3, sc8 = tid & 7;
  int scol = (sc8 ^ (srow & 7)) * 8;       // source-side XOR swizzle (16B granule)

  f32x4 zero = {0.f, 0.f, 0.f, 0.f};
  const float csc = 0.125f * 1.44269504088896f;  // 1/sqrt(64) * log2(e)

  bf16x8 ones;
#pragma unroll
  for (int i = 0; i < 8; ++i) ones[i] = (short)0x3F80;  // bf16 1.0

  // prologue: stage tile kv0=0 into buffer 0 (first tile of job A)
  gload16(kbase + (size_t)srow * HD_ + scol, sK[0] + tid * 8);
  gload16(vbase + (size_t)srow * T_ + scol, sV[0] + tid * 8);
  __syncthreads();   // implicit vmcnt(0) drain

  int cur = 0;
#pragma unroll
  for (int s = 0; s < 2; ++s) {
    const int qtile = s ? jqB : jqA;
    const int q0 = qtile * 128;
    const int nkv = 2 * qtile + 2;

    f32x4 o[4], o_l;
#pragma unroll
    for (int j = 0; j < 4; ++j) o[j] = zero;
    o_l = zero;
    float mrow[4] = {-1e30f, -1e30f, -1e30f, -1e30f};

    for (int kvt = 0; kvt < nkv; ++kvt) {
      int kv0 = kvt * 64;
      // prefetch next tile (chains into job B's kv0=0 at the boundary)
      int nxt = (kvt + 1 < nkv) ? (kv0 + 64) : (s == 0 ? 0 : -1);
      if (nxt >= 0) {
        gload16(kbase + (size_t)(nxt + srow) * HD_ + scol, sK[cur ^ 1] + tid * 8);
        gload16(vbase + (size_t)srow * T_ + nxt + scol, sV[cur ^ 1] + tid * 8);
      }

      bool wave_skip = (kv0 > q0 + 16 * w + 15);   // wave entirely above diagonal
      if (!wave_skip) {
        const u16* sk = sK[cur];
        f32x4 sc[4];
        __builtin_amdgcn_s_setprio(1);
#pragma unroll
        for (int j = 0; j < 4; ++j) {
          int rowk = j * 16 + li;
          bf16x8 kf0 = *(const bf16x8*)(sk + rowk * 64 + ((quad ^ (rowk & 7)) * 8));
          bf16x8 kf1 = *(const bf16x8*)(sk + rowk * 64 + (((4 + quad) ^ (rowk & 7)) * 8));
          f32x4 z = zero;
          z = __builtin_amdgcn_mfma_f32_16x16x32_bf16(qf[s][0], kf0, z, 0, 0, 0);
          z = __builtin_amdgcn_mfma_f32_16x16x32_bf16(qf[s][1], kf1, z, 0, 0, 0);
          sc[j] = z;
        }
        __builtin_amdgcn_s_setprio(0);

        if (kvt >= nkv - 2) {                      // diagonal band: causal mask
#pragma unroll
          for (int j = 0; j < 4; ++j)
#pragma unroll
            for (int r = 0; r < 4; ++r) {
              int qrow = q0 + 16 * w + quad * 4 + r;
              int kcol = kv0 + j * 16 + li;
              if (kcol > qrow) sc[j][r] = -1e30f;
            }
        }

        // row max over the 16-lane (li) group; defer-max decision
        float vmax[4], g = -1e30f;
#pragma unroll
        for (int r = 0; r < 4; ++r) {
          float v = fmaxf(fmaxf(sc[0][r], sc[1][r]), fmaxf(sc[2][r], sc[3][r]));
#pragma unroll
          for (int off = 1; off < 16; off <<= 1) v = fmaxf(v, __shfl_xor(v, off, 16));
          vmax[r] = v;
          g = fmaxf(g, v - mrow[r]);
        }
        if (!__all(g * csc <= 8.0f)) {             // rescale only on real growth
#pragma unroll
          for (int r = 0; r < 4; ++r) {
            float mnew = fmaxf(mrow[r], vmax[r]);
            float alpha = exp2f((mrow[r] - mnew) * csc);
            mrow[r] = mnew;
#pragma unroll
            for (int j = 0; j < 4; ++j) o[j][r] *= alpha;
            o_l[r] *= alpha;
          }
        }

        // P = exp2(s*csc - m*csc)  (bounded by 2^8 under defer-max),
        // packed f32->bf16 via v_cvt_pk_bf16_f32, write own-wave sP stripe
#pragma unroll
        for (int r = 0; r < 4; ++r) {
          float mc = mrow[r] * csc;
          int prow = 16 * w + quad * 4 + r;
          int rowbase = prow * 64;
          int swz = (prow & 7) * 8;
          float p0 = exp2f(__builtin_fmaf(sc[0][r], csc, -mc));
          float p1 = exp2f(__builtin_fmaf(sc[1][r], csc, -mc));
          float p2 = exp2f(__builtin_fmaf(sc[2][r], csc, -mc));
          float p3 = exp2f(__builtin_fmaf(sc[3][r], csc, -mc));
          unsigned pk01, pk23;
          asm("v_cvt_pk_bf16_f32 %0, %1, %2" : "=v"(pk01) : "v"(p0), "v"(p1));
          asm("v_cvt_pk_bf16_f32 %0, %1, %2" : "=v"(pk23) : "v"(p2), "v"(p3));
          sP[rowbase + ((li) ^ swz)]      = (u16)(pk01 & 0xffffu);
          sP[rowbase + ((16 + li) ^ swz)] = (u16)(pk01 >> 16);
          sP[rowbase + ((32 + li) ^ swz)] = (u16)(pk23 & 0xffffu);
          sP[rowbase + ((48 + li) ^ swz)] = (u16)(pk23 >> 16);
        }

        // PV + row-sum: own-wave stripe only -> in-wave LDS ordering suffices
        int prow2 = 16 * w + li;
        bf16x8 pf0 = *(const bf16x8*)(sP + prow2 * 64 + ((quad ^ (prow2 & 7)) * 8));
        bf16x8 pf1 = *(const bf16x8*)(sP + prow2 * 64 + (((4 + quad) ^ (prow2 & 7)) * 8));
        const u16* sv = sV[cur];
        __builtin_amdgcn_s_setprio(1);
#pragma unroll
        for (int j = 0; j < 4; ++j) {
          int rowv = j * 16 + li;
          bf16x8 vf0 = *(const bf16x8*)(sv + rowv * 64 + ((quad ^ (rowv & 7)) * 8));
          bf16x8 vf1 = *(const bf16x8*)(sv + rowv * 64 + (((4 + quad) ^ (rowv & 7)) * 8));
          o[j] = __builtin_amdgcn_mfma_f32_16x16x32_bf16(pf0, vf0, o[j], 0, 0, 0);
          o[j] = __builtin_amdgcn_mfma_f32_16x16x32_bf16(pf1, vf1, o[j], 0, 0, 0);
        }
        o_l = __builtin_amdgcn_mfma_f32_16x16x32_bf16(pf0, ones, o_l, 0, 0, 0);
        o_l = __builtin_amdgcn_mfma_f32_16x16x32_bf16(pf1, ones, o_l, 0, 0, 0);
        __builtin_amdgcn_s_setprio(0);
      }

      __syncthreads();   // drains prefetch vmcnt + guards buffer swap
      cur ^= 1;
    }

    // epilogue for this job
    int b = bh >> 4, h = bh & (NH_ - 1);
    float rinv[4];
#pragma unroll
    for (int r = 0; r < 4; ++r) rinv[r] = 1.0f / fmaxf(o_l[r], 1e-20f);
#pragma unroll
    for (int j = 0; j < 4; ++j)
#pragma unroll
      for (int r = 0; r < 4; ++r) {
        int t = q0 + 16 * w + quad * 4 + r;
        int d = j * 16 + li;
        Y[((size_t)b * T_ + t) * C_ + h * HD_ + d] = f2bf(o[j][r] * rinv[r]);
      }
  }
}

// ---------------------------------------------------------------------------
extern "C" void kernel_launch(void* const* d_in, const int* in_sizes, int n_in,
                              void* d_out, int out_size, void* d_ws, size_t ws_size,
                              hipStream_t stream) {
  (void)in_sizes; (void)n_in; (void)out_size; (void)ws_size;
  const float* x      = (const float*)d_in[0];   // [B,T,C] f32
  const float* w_attn = (const float*)d_in[1];   // [C,3C]  f32
  const float* w_proj = (const float*)d_in[2];   // [C,C]   f32
  float* out = (float*)d_out;                    // [B,T,C] f32

  const size_t NTOK = (size_t)B_ * T_ * C_;      // 8.39M elems
  u16* watT   = (u16*)d_ws;                      // 3.15M
  u16* wprojT = watT   + (size_t)3 * C_ * C_;    // 1.05M
  u16* xbf    = wprojT + (size_t)C_ * C_;        // 8.39M (yb overlays this)
  u16* qb     = xbf  + NTOK;                     // 8.39M [b,h,t,d]
  u16* kb     = qb   + NTOK;                     // 8.39M [b,h,t,d]
  u16* vtb    = kb   + NTOK;                     // 8.39M [b,h,d,t]
  u16* yb     = xbf;                             // overlay: xbf dead after qkv
  // total ws: 37.8M u16 = 75.5 MB

  transpose_w<<<dim3(16, 48), 256, 0, stream>>>(w_attn, watT, C_, 3 * C_);
  transpose_w<<<dim3(16, 16), 256, 0, stream>>>(w_proj, wprojT, C_, C_);
  convert_x<<<dim3(4096), 256, 0, stream>>>(x, xbf);
  gemm_qkv<<<dim3(64, 24), 256, 0, stream>>>(xbf, watT, qb, kb, vtb);
  attn_k<<<dim3(8, 64), 512, 0, stream>>>(qb, kb, vtb, yb);
  gemm_proj<<<dim3(64, 8), 256, 0, stream>>>(yb, wprojT, out);
}